// Round 11
// baseline (310.299 us; speedup 1.0000x reference)
//
#include <hip/hip_runtime.h>
#include <hip/hip_bf16.h>
#include <math.h>

// Problem constants (reference: B,S,D,H,FD = 2,2048,1024,16,64; DK=64, ALPHA=1)
#define Bb 2
#define Ss 2048
#define Dd 1024
#define Hh 16
#define DK 64
#define FD 64

typedef short short8 __attribute__((ext_vector_type(8)));   // 8 bf16 (4 VGPRs)
typedef float f32x4 __attribute__((ext_vector_type(4)));

static __device__ inline ushort f2bf(float f) {
    union { float f; unsigned u; } v; v.f = f;
    unsigned r = v.u + 0x7FFF + ((v.u >> 16) & 1);   // round-to-nearest-even
    return (ushort)(r >> 16);
}
static __device__ inline uint fbits(float f) {
    union { float f; uint u; } v; v.f = f; return v.u;
}

// ---------------------------------------------------------------------------
// cast fp32 -> bf16, 2 elems/thread
// ---------------------------------------------------------------------------
__global__ __launch_bounds__(256) void cast_bf16(const float* __restrict__ in,
                                                 ushort* __restrict__ out) {
    size_t p = (size_t)blockIdx.x * 256 + threadIdx.x;
    float2 v = *(const float2*)(in + 2 * p);
    ((uint*)out)[p] = (uint)f2bf(v.x) | ((uint)f2bf(v.y) << 16);
}

// ---------------------------------------------------------------------------
// transpose+cast 4 weights W[K][N] fp32 -> WT[id][N][K] bf16 (64x64 LDS tiles)
// ---------------------------------------------------------------------------
__global__ __launch_bounds__(256) void transpose_cast4(const float* __restrict__ W0,
                                                       const float* __restrict__ W1,
                                                       const float* __restrict__ W2,
                                                       const float* __restrict__ W3,
                                                       ushort* __restrict__ WT) {
    __shared__ float T[64][65];
    const float* W = blockIdx.z == 0 ? W0 : blockIdx.z == 1 ? W1 : blockIdx.z == 2 ? W2 : W3;
    ushort* dst = WT + (size_t)blockIdx.z * Dd * Dd;
    const int k0 = blockIdx.x * 64, n0 = blockIdx.y * 64;
    const int tid = threadIdx.x;
#pragma unroll
    for (int i = 0; i < 4; ++i) {
        int kr = i * 16 + (tid >> 4);
        int nc = (tid & 15) * 4;
        float4 v = *(const float4*)(W + (size_t)(k0 + kr) * Dd + n0 + nc);
        T[kr][nc] = v.x; T[kr][nc + 1] = v.y; T[kr][nc + 2] = v.z; T[kr][nc + 3] = v.w;
    }
    __syncthreads();
    int nr = tid >> 2;
    int kc = (tid & 3) * 16;
    uint pk[8];
#pragma unroll
    for (int j = 0; j < 8; ++j)
        pk[j] = (uint)f2bf(T[kc + 2 * j][nr]) | ((uint)f2bf(T[kc + 2 * j + 1][nr]) << 16);
    uint* o = (uint*)(dst + (size_t)(n0 + nr) * Dd + k0 + kc);
    *(int4*)o = *(int4*)&pk[0];
    *(int4*)(o + 4) = *(int4*)&pk[4];
}

// ---------------------------------------------------------------------------
// l2norm rows of both features->fn and requirements->rn in one launch
// ---------------------------------------------------------------------------
__global__ __launch_bounds__(256) void l2norm2(const float* __restrict__ fsrc,
                                               const float* __restrict__ rsrc,
                                               float* __restrict__ fn,
                                               float* __restrict__ rn) {
    int row = blockIdx.x * 4 + (threadIdx.x >> 6);
    int lane = threadIdx.x & 63;
    const float* in = fsrc; float* out = fn; int r = row;
    if (row >= Bb * Ss) { in = rsrc; out = rn; r = row - Bb * Ss; }
    float v = in[(size_t)r * FD + lane];
    float s = v * v;
#pragma unroll
    for (int off = 32; off; off >>= 1) s += __shfl_xor(s, off, 64);
    out[(size_t)r * FD + lane] = v / fmaxf(sqrtf(s), 1e-12f);
}

// ---------------------------------------------------------------------------
// aux halves of Qext/Kext: ext[bh][s][64:128] = rn/fn row, bf16 (coalesced)
// ---------------------------------------------------------------------------
__global__ __launch_bounds__(256) void pack_aux(const float* __restrict__ rn,
                                                const float* __restrict__ fn,
                                                ushort* __restrict__ Qext,
                                                ushort* __restrict__ Kext) {
    size_t p = (size_t)blockIdx.x * 256 + threadIdx.x;   // over B*H*S*32 uints
    int j = (int)(p & 31);
    size_t row = p >> 5;                 // bh*S + s
    int s = (int)(row & (Ss - 1));
    int bh = (int)(row >> 11);
    int b = bh >> 4;
    size_t src = ((size_t)(b * Ss + s)) * FD + j * 2;
    float2 r2 = *(const float2*)(rn + src);
    float2 f2 = *(const float2*)(fn + src);
    ((uint*)Qext)[row * 64 + 32 + j] = (uint)f2bf(r2.x) | ((uint)f2bf(r2.y) << 16);
    ((uint*)Kext)[row * 64 + 32 + j] = (uint)f2bf(f2.x) | ((uint)f2bf(f2.y) << 16);
}

// ---------------------------------------------------------------------------
// pack_vt: Vt[bh][d][s] = Vrow[bh][s][d]  (bf16 64x64 tile transpose via LDS)
// ---------------------------------------------------------------------------
__global__ __launch_bounds__(256) void pack_vt(const ushort* __restrict__ Vrow,
                                               ushort* __restrict__ Vt) {
    __shared__ ushort T[64][72];
    const int tid = threadIdx.x;
    const int s0 = blockIdx.x * 64;
    const int h = blockIdx.y, b = blockIdx.z;
#pragma unroll
    for (int i = 0; i < 2; ++i) {
        int f = tid + i * 256;
        int sr = f >> 3, dc = (f & 7) * 8;
        *(int4*)&T[sr][dc] =
            *(const int4*)(Vrow + ((size_t)((b * Hh + h) * Ss) + s0 + sr) * 64 + dc);
    }
    __syncthreads();
    int d = tid >> 2;
    int sg = (tid & 3) * 16;
    uint pk[8];
#pragma unroll
    for (int j = 0; j < 8; ++j)
        pk[j] = (uint)T[sg + 2 * j][d] | ((uint)T[sg + 2 * j + 1][d] << 16);
    uint* dst = (uint*)(Vt + ((size_t)((b * Hh + h) * DK + d)) * Ss + s0 + sg);
    *(int4*)dst = *(int4*)&pk[0];
    *(int4*)(dst + 4) = *(int4*)&pk[4];
}

// ---------------------------------------------------------------------------
// Fused QKV bf16 MFMA GEMM. 128x128 tile, BK=64, 4 waves, coalesced LDS
// epilogue (round-10). id0 -> Qext (x0.125), id1 -> Kext, id2 -> Vrow bf16.
// ---------------------------------------------------------------------------
__global__ __launch_bounds__(256) void gemm_qkv(const ushort* __restrict__ xb,
                                                const ushort* __restrict__ WT,
                                                const float* __restrict__ bq,
                                                const float* __restrict__ bk,
                                                const float* __restrict__ bv,
                                                ushort* __restrict__ Qext,
                                                ushort* __restrict__ Kext,
                                                ushort* __restrict__ Vrow) {
    __shared__ ushort smem[2][128][72];   // As=smem[0], Bs=smem[1]; 36.9KB
    ushort (*As)[72] = smem[0];
    ushort (*Bs)[72] = smem[1];
    const int tid = threadIdx.x;
    const int lane = tid & 63, wave = tid >> 6;
    const int col = lane & 15, quad = lane >> 4;
    const int wm = wave >> 1, wn = wave & 1;
    const int id = blockIdx.x >> 3;               // 0:Q 1:K 2:V
    const int n0 = (blockIdx.x & 7) * 128;
    const int m0 = blockIdx.y * 128;
    const ushort* BTw = WT + (size_t)id * Dd * Dd;
    const float* bias = id == 0 ? bq : id == 1 ? bk : bv;

    f32x4 acc[4][4] = {};

    for (int k0 = 0; k0 < Dd; k0 += 64) {
        __syncthreads();
#pragma unroll
        for (int i = 0; i < 4; ++i) {
            int f = tid + i * 256;          // 0..1023
            int r = f >> 3, c = (f & 7) * 8;
            *(int4*)&As[r][c] = *(const int4*)(xb + (size_t)(m0 + r) * Dd + k0 + c);
            *(int4*)&Bs[r][c] = *(const int4*)(BTw + (size_t)(n0 + r) * Dd + k0 + c);
        }
        __syncthreads();
#pragma unroll
        for (int kk = 0; kk < 2; ++kk) {
            short8 af[4], bf[4];
#pragma unroll
            for (int i = 0; i < 4; ++i) {
                af[i] = *(const short8*)&As[wm * 64 + i * 16 + col][kk * 32 + quad * 8];
                bf[i] = *(const short8*)&Bs[wn * 64 + i * 16 + col][kk * 32 + quad * 8];
            }
#pragma unroll
            for (int i = 0; i < 4; ++i)
#pragma unroll
                for (int j = 0; j < 4; ++j)
                    acc[i][j] = __builtin_amdgcn_mfma_f32_16x16x32_bf16(af[i], bf[j], acc[i][j], 0, 0, 0);
        }
    }

    // ---- coalesced epilogue via LDS ----
    __syncthreads();                               // As/Bs reads all done
    ushort (*Ep)[136] = (ushort (*)[136])&smem[0][0][0];   // 128x136 = 34.8KB
    const float scl = (id == 0) ? 0.125f : 1.0f;
#pragma unroll
    for (int j = 0; j < 4; ++j) {
        int n_local = wn * 64 + j * 16 + col;
        float bvl = bias[n0 + n_local];
#pragma unroll
        for (int i = 0; i < 4; ++i) {
            int mb = wm * 64 + i * 16 + quad * 4;
#pragma unroll
            for (int reg = 0; reg < 4; ++reg)
                Ep[mb + reg][n_local] = f2bf((acc[i][j][reg] + bvl) * scl);
        }
    }
    __syncthreads();
    {
        const int mrow = tid >> 1;               // 0..127 local s
        const int half = tid & 1;                // which head of the 2 in n-range
        const int b = m0 >> 11, s = (m0 & (Ss - 1)) + mrow;
        const int hh = (n0 >> 6) + half;
        if (id == 2) {
            ushort* drow = Vrow + ((size_t)(b * Hh + hh) * Ss + s) * 64;
#pragma unroll
            for (int k = 0; k < 8; ++k)
                *(int4*)(drow + k * 8) = *(int4*)&Ep[mrow][half * 64 + k * 8];
        } else {
            ushort* drow = (id == 0 ? Qext : Kext) + ((size_t)(b * Hh + hh) * Ss + s) * 128;
#pragma unroll
            for (int k = 0; k < 8; ++k)
                *(int4*)(drow + k * 8) = *(int4*)&Ep[mrow][half * 64 + k * 8];
        }
    }
}

// ---------------------------------------------------------------------------
// Output projection: out[M][N] f32 = abb(bf16) @ WoT + bo (round-8 version).
// ---------------------------------------------------------------------------
__global__ __launch_bounds__(256) void gemm_out(const ushort* __restrict__ Ab,
                                                const ushort* __restrict__ BT,
                                                const float* __restrict__ bias,
                                                float* __restrict__ C) {
    __shared__ ushort As[128][72];
    __shared__ ushort Bs[128][72];
    const int tid = threadIdx.x;
    const int lane = tid & 63, wave = tid >> 6;
    const int col = lane & 15, quad = lane >> 4;
    const int wm = wave >> 1, wn = wave & 1;
    const int n0 = blockIdx.x * 128;
    const int m0 = blockIdx.y * 128;

    f32x4 acc[4][4] = {};

    for (int k0 = 0; k0 < Dd; k0 += 64) {
        __syncthreads();
#pragma unroll
        for (int i = 0; i < 4; ++i) {
            int f = tid + i * 256;
            int r = f >> 3, c = (f & 7) * 8;
            *(int4*)&As[r][c] = *(const int4*)(Ab + (size_t)(m0 + r) * Dd + k0 + c);
            *(int4*)&Bs[r][c] = *(const int4*)(BT + (size_t)(n0 + r) * Dd + k0 + c);
        }
        __syncthreads();
#pragma unroll
        for (int kk = 0; kk < 2; ++kk) {
            short8 af[4], bf[4];
#pragma unroll
            for (int i = 0; i < 4; ++i) {
                af[i] = *(const short8*)&As[wm * 64 + i * 16 + col][kk * 32 + quad * 8];
                bf[i] = *(const short8*)&Bs[wn * 64 + i * 16 + col][kk * 32 + quad * 8];
            }
#pragma unroll
            for (int i = 0; i < 4; ++i)
#pragma unroll
                for (int j = 0; j < 4; ++j)
                    acc[i][j] = __builtin_amdgcn_mfma_f32_16x16x32_bf16(af[i], bf[j], acc[i][j], 0, 0, 0);
        }
    }

#pragma unroll
    for (int j = 0; j < 4; ++j) {
        int n = n0 + wn * 64 + j * 16 + col;
        float bvl = bias[n];
#pragma unroll
        for (int i = 0; i < 4; ++i) {
#pragma unroll
            for (int reg = 0; reg < 4; ++reg) {
                int m = m0 + wm * 64 + i * 16 + quad * 4 + reg;
                C[(size_t)m * Dd + n] = acc[i][j][reg] + bvl;
            }
        }
    }
}

// ---------------------------------------------------------------------------
// Flash attention v6: round-8 S^T structure + (a) kf/vtf HOISTED out of the
// rt loop (fragment loads don't depend on rt; was 2x re-read -> 40% of the
// DS-pipe traffic, the dominant consumable per round-10 analysis) and
// (b) truncation-based P^T pack (2 VALU/pair vs ~9 for RNE; lsum stays fp32).
// ---------------------------------------------------------------------------
#define ABQ 128

__global__ __launch_bounds__(256, 2) void attn_mfma6(const ushort* __restrict__ Qe,
                                                     const ushort* __restrict__ Ke,
                                                     const ushort* __restrict__ Vt,
                                                     ushort* __restrict__ Ob) {
    __shared__ ushort Ks[64][136];       // K-ext tile [key][128+8pad]
    __shared__ ushort Vts[64][72];       // V^T tile [d][64key+8pad]
    __shared__ ushort PsT[4][16][72];    // per-wave P^T [q][64keys+8pad], bf16

    const int tid = threadIdx.x;
    const int wave = tid >> 6, lane = tid & 63;
    const int col = lane & 15, quad = lane >> 4;
    const int qt = (gridDim.x - 1) - blockIdx.x;   // long blocks first
    const int h = blockIdx.y, b = blockIdx.z;
    const int bh = b * Hh + h;
    const int q0 = qt * ABQ;

    short8 qf[2][4];
#pragma unroll
    for (int rt = 0; rt < 2; ++rt) {
        const ushort* qp = Qe + ((size_t)bh * Ss + q0 + wave * 32 + rt * 16 + col) * 128 + quad * 8;
#pragma unroll
        for (int k0 = 0; k0 < 4; ++k0) qf[rt][k0] = *(const short8*)(qp + k0 * 32);
    }

    const f32x4 zero4 = {0.f, 0.f, 0.f, 0.f};
    f32x4 oaccT[2][4] = {{zero4, zero4, zero4, zero4}, {zero4, zero4, zero4, zero4}};
    float lsum[2] = {0.f, 0.f};          // per-lane: q = rowb + col

    const ushort* Kbase = Ke + (size_t)bh * Ss * 128;
    const ushort* Vbase = Vt + (size_t)bh * 64 * Ss;

    const int ntiles = 2 * qt + 2;
    for (int t = 0; t < ntiles; ++t) {
        const int j0 = t * 64;
        __syncthreads();
#pragma unroll
        for (int i = 0; i < 4; ++i) {
            int f = tid + i * 256;
            int r = f >> 4, ch = f & 15;
            *(int4*)&Ks[r][ch * 8] = *(const int4*)(Kbase + (size_t)(j0 + r) * 128 + ch * 8);
        }
#pragma unroll
        for (int i = 0; i < 2; ++i) {
            int f = tid + i * 256;
            int d = f >> 3, ch = f & 7;
            *(int4*)&Vts[d][ch * 8] = *(const int4*)(Vbase + (size_t)d * Ss + j0 + ch * 8);
        }
        __syncthreads();

        // whole-wave guard: even rt=1 (rows ..+31) fully masked -> skip all
        if (j0 > q0 + wave * 32 + 31) continue;

        // hoisted fragment loads: shared by both row-tiles
        short8 kf[4][4], vtf[2][4];
#pragma unroll
        for (int c = 0; c < 4; ++c)
#pragma unroll
            for (int k0 = 0; k0 < 4; ++k0)
                kf[c][k0] = *(const short8*)&Ks[c * 16 + col][k0 * 32 + quad * 8];
#pragma unroll
        for (int k0 = 0; k0 < 2; ++k0)
#pragma unroll
            for (int c2 = 0; c2 < 4; ++c2)
                vtf[k0][c2] = *(const short8*)&Vts[c2 * 16 + col][k0 * 32 + quad * 8];

        const bool diag = (t >= ntiles - 2);
#pragma unroll
        for (int rt = 0; rt < 2; ++rt) {
            const int rowb = q0 + wave * 32 + rt * 16;
            if (j0 > rowb + 15) continue;        // fully masked row-tile

            f32x4 sacc[4] = {zero4, zero4, zero4, zero4};
#pragma unroll
            for (int c = 0; c < 4; ++c)
#pragma unroll
                for (int k0 = 0; k0 < 4; ++k0)
                    sacc[c] = __builtin_amdgcn_mfma_f32_16x16x32_bf16(kf[c][k0], qf[rt][k0], sacc[c], 0, 0, 0);

            const int qrow_rel = rowb + col - j0;   // mask: key_rel > qrow_rel
#pragma unroll
            for (int c = 0; c < 4; ++c) {
#pragma unroll
                for (int reg = 0; reg < 4; ++reg) {
                    float s = sacc[c][reg];
                    if (diag && (c * 16 + quad * 4 + reg > qrow_rel)) s = -1e9f;
                    float p = __expf(fminf(s, 20.f) - 8.0f);
                    lsum[rt] += p;
                    sacc[c][reg] = p;
                }
                // truncation pack (top 16 bits of f32 = bf16-RTZ), 2 keys/uint
                uint2 pk;
                pk.x = (fbits(sacc[c][0]) >> 16) | (fbits(sacc[c][1]) & 0xffff0000u);
                pk.y = (fbits(sacc[c][2]) >> 16) | (fbits(sacc[c][3]) & 0xffff0000u);
                *(uint2*)&PsT[wave][col][c * 16 + quad * 4] = pk;
            }

#pragma unroll
            for (int k0 = 0; k0 < 2; ++k0) {
                short8 ptf = *(const short8*)&PsT[wave][col][k0 * 32 + quad * 8];
#pragma unroll
                for (int c2 = 0; c2 < 4; ++c2)
                    oaccT[rt][c2] = __builtin_amdgcn_mfma_f32_16x16x32_bf16(vtf[k0][c2], ptf, oaccT[rt][c2], 0, 0, 0);
            }
        }
    }

#pragma unroll
    for (int rt = 0; rt < 2; ++rt) {
        float l = lsum[rt];
        l += __shfl_xor(l, 16, 64);
        l += __shfl_xor(l, 32, 64);              // sum over the 4 quads (same col)
        const float inv = 1.f / l;
        const int rowb = q0 + wave * 32 + rt * 16;
        ushort* dst = Ob + ((size_t)b * Ss + rowb + col) * Dd + h * DK + quad * 4;
#pragma unroll
        for (int c2 = 0; c2 < 4; ++c2) {
            uint2 pk;
            pk.x = (uint)f2bf(oaccT[rt][c2][0] * inv) | ((uint)f2bf(oaccT[rt][c2][1] * inv) << 16);
            pk.y = (uint)f2bf(oaccT[rt][c2][2] * inv) | ((uint)f2bf(oaccT[rt][c2][3] * inv) << 16);
            *(uint2*)(dst + c2 * 16) = pk;
        }
    }
}

// ---------------------------------------------------------------------------
extern "C" void kernel_launch(void* const* d_in, const int* in_sizes, int n_in,
                              void* d_out, int out_size, void* d_ws, size_t ws_size,
                              hipStream_t stream) {
    const float* x            = (const float*)d_in[0];
    const float* features     = (const float*)d_in[1];
    const float* requirements = (const float*)d_in[2];
    const float* Wq = (const float*)d_in[3];
    const float* bq = (const float*)d_in[4];
    const float* Wk = (const float*)d_in[5];
    const float* bk = (const float*)d_in[6];
    const float* Wv = (const float*)d_in[7];
    const float* bv = (const float*)d_in[8];
    const float* Wo = (const float*)d_in[9];
    const float* bo = (const float*)d_in[10];

    float* out = (float*)d_out;
    float* ws = (float*)d_ws;

    // workspace layout (float offsets)
    ushort* xb   = (ushort*)(ws);                 // [4096,1024] bf16, 8MB
    ushort* WT   = (ushort*)(ws + 2097152);       // [4][1024][1024] bf16, 8MB
    ushort* Qext = (ushort*)(ws + 4194304);       // [32][2048][128] bf16, 16MB
    ushort* Kext = (ushort*)(ws + 8388608);       // 16MB
    ushort* Vrow = (ushort*)(ws + 12582912);      // [32][2048][64] bf16, 8MB
    ushort* Vt   = (ushort*)(ws + 16777216);      // [32][64][2048] bf16, 8MB
    float*  fn   =           ws + 18874368;       // [4096][64] f32
    float*  rn   =           ws + 19136512;
    ushort* abb  = (ushort*)(ws + 12582912);      // attn out bf16, reuses Vrow (dead after pack_vt)

    cast_bf16<<<8192, 256, 0, stream>>>(x, xb);
    transpose_cast4<<<dim3(16, 16, 4), 256, 0, stream>>>(Wq, Wk, Wv, Wo, WT);
    l2norm2<<<2048, 256, 0, stream>>>(features, requirements, fn, rn);
    pack_aux<<<8192, 256, 0, stream>>>(rn, fn, Qext, Kext);

    gemm_qkv<<<dim3(24, 32), 256, 0, stream>>>(xb, WT, bq, bk, bv, Qext, Kext, Vrow);
    pack_vt<<<dim3(Ss / 64, Hh, Bb), 256, 0, stream>>>(Vrow, Vt);

    attn_mfma6<<<dim3(Ss / ABQ, Hh, Bb), 256, 0, stream>>>(Qext, Kext, Vt, abb);

    gemm_out<<<dim3(8, 32), 256, 0, stream>>>(abb, WT + (size_t)3 * Dd * Dd, bo, out);
}

// Round 12
// 279.313 us; speedup vs baseline: 1.1109x; 1.1109x over previous
//
#include <hip/hip_runtime.h>
#include <hip/hip_bf16.h>
#include <math.h>

// Problem constants (reference: B,S,D,H,FD = 2,2048,1024,16,64; DK=64, ALPHA=1)
#define Bb 2
#define Ss 2048
#define Dd 1024
#define Hh 16
#define DK 64
#define FD 64

typedef short short8 __attribute__((ext_vector_type(8)));   // 8 bf16 (4 VGPRs)
typedef float f32x4 __attribute__((ext_vector_type(4)));

static __device__ inline ushort f2bf(float f) {
    union { float f; unsigned u; } v; v.f = f;
    unsigned r = v.u + 0x7FFF + ((v.u >> 16) & 1);   // round-to-nearest-even
    return (ushort)(r >> 16);
}

// ---------------------------------------------------------------------------
// cast fp32 -> bf16, 2 elems/thread
// ---------------------------------------------------------------------------
__global__ __launch_bounds__(256) void cast_bf16(const float* __restrict__ in,
                                                 ushort* __restrict__ out) {
    size_t p = (size_t)blockIdx.x * 256 + threadIdx.x;
    float2 v = *(const float2*)(in + 2 * p);
    ((uint*)out)[p] = (uint)f2bf(v.x) | ((uint)f2bf(v.y) << 16);
}

// ---------------------------------------------------------------------------
// transpose+cast 4 weights W[K][N] fp32 -> WT[id][N][K] bf16 (64x64 LDS tiles)
// ---------------------------------------------------------------------------
__global__ __launch_bounds__(256) void transpose_cast4(const float* __restrict__ W0,
                                                       const float* __restrict__ W1,
                                                       const float* __restrict__ W2,
                                                       const float* __restrict__ W3,
                                                       ushort* __restrict__ WT) {
    __shared__ float T[64][65];
    const float* W = blockIdx.z == 0 ? W0 : blockIdx.z == 1 ? W1 : blockIdx.z == 2 ? W2 : W3;
    ushort* dst = WT + (size_t)blockIdx.z * Dd * Dd;
    const int k0 = blockIdx.x * 64, n0 = blockIdx.y * 64;
    const int tid = threadIdx.x;
#pragma unroll
    for (int i = 0; i < 4; ++i) {
        int kr = i * 16 + (tid >> 4);
        int nc = (tid & 15) * 4;
        float4 v = *(const float4*)(W + (size_t)(k0 + kr) * Dd + n0 + nc);
        T[kr][nc] = v.x; T[kr][nc + 1] = v.y; T[kr][nc + 2] = v.z; T[kr][nc + 3] = v.w;
    }
    __syncthreads();
    int nr = tid >> 2;
    int kc = (tid & 3) * 16;
    uint pk[8];
#pragma unroll
    for (int j = 0; j < 8; ++j)
        pk[j] = (uint)f2bf(T[kc + 2 * j][nr]) | ((uint)f2bf(T[kc + 2 * j + 1][nr]) << 16);
    uint* o = (uint*)(dst + (size_t)(n0 + nr) * Dd + k0 + kc);
    *(int4*)o = *(int4*)&pk[0];
    *(int4*)(o + 4) = *(int4*)&pk[4];
}

// ---------------------------------------------------------------------------
// l2norm rows of both features->fn and requirements->rn in one launch
// ---------------------------------------------------------------------------
__global__ __launch_bounds__(256) void l2norm2(const float* __restrict__ fsrc,
                                               const float* __restrict__ rsrc,
                                               float* __restrict__ fn,
                                               float* __restrict__ rn) {
    int row = blockIdx.x * 4 + (threadIdx.x >> 6);
    int lane = threadIdx.x & 63;
    const float* in = fsrc; float* out = fn; int r = row;
    if (row >= Bb * Ss) { in = rsrc; out = rn; r = row - Bb * Ss; }
    float v = in[(size_t)r * FD + lane];
    float s = v * v;
#pragma unroll
    for (int off = 32; off; off >>= 1) s += __shfl_xor(s, off, 64);
    out[(size_t)r * FD + lane] = v / fmaxf(sqrtf(s), 1e-12f);
}

// ---------------------------------------------------------------------------
// aux halves of Qext/Kext: ext[bh][s][64:128] = rn/fn row, bf16 (coalesced)
// ---------------------------------------------------------------------------
__global__ __launch_bounds__(256) void pack_aux(const float* __restrict__ rn,
                                                const float* __restrict__ fn,
                                                ushort* __restrict__ Qext,
                                                ushort* __restrict__ Kext) {
    size_t p = (size_t)blockIdx.x * 256 + threadIdx.x;   // over B*H*S*32 uints
    int j = (int)(p & 31);
    size_t row = p >> 5;                 // bh*S + s
    int s = (int)(row & (Ss - 1));
    int bh = (int)(row >> 11);
    int b = bh >> 4;
    size_t src = ((size_t)(b * Ss + s)) * FD + j * 2;
    float2 r2 = *(const float2*)(rn + src);
    float2 f2 = *(const float2*)(fn + src);
    ((uint*)Qext)[row * 64 + 32 + j] = (uint)f2bf(r2.x) | ((uint)f2bf(r2.y) << 16);
    ((uint*)Kext)[row * 64 + 32 + j] = (uint)f2bf(f2.x) | ((uint)f2bf(f2.y) << 16);
}

// ---------------------------------------------------------------------------
// pack_vt: Vt[bh][d][s] = Vrow[bh][s][d]  (bf16 64x64 tile transpose via LDS)
// ---------------------------------------------------------------------------
__global__ __launch_bounds__(256) void pack_vt(const ushort* __restrict__ Vrow,
                                               ushort* __restrict__ Vt) {
    __shared__ ushort T[64][72];
    const int tid = threadIdx.x;
    const int s0 = blockIdx.x * 64;
    const int h = blockIdx.y, b = blockIdx.z;
#pragma unroll
    for (int i = 0; i < 2; ++i) {
        int f = tid + i * 256;
        int sr = f >> 3, dc = (f & 7) * 8;
        *(int4*)&T[sr][dc] =
            *(const int4*)(Vrow + ((size_t)((b * Hh + h) * Ss) + s0 + sr) * 64 + dc);
    }
    __syncthreads();
    int d = tid >> 2;
    int sg = (tid & 3) * 16;
    uint pk[8];
#pragma unroll
    for (int j = 0; j < 8; ++j)
        pk[j] = (uint)T[sg + 2 * j][d] | ((uint)T[sg + 2 * j + 1][d] << 16);
    uint* dst = (uint*)(Vt + ((size_t)((b * Hh + h) * DK + d)) * Ss + s0 + sg);
    *(int4*)dst = *(int4*)&pk[0];
    *(int4*)(dst + 4) = *(int4*)&pk[4];
}

// ---------------------------------------------------------------------------
// Fused QKV bf16 MFMA GEMM. 128x128 tile, BK=64, 4 waves, coalesced LDS
// epilogue (round-10). id0 -> Qext (x0.125), id1 -> Kext, id2 -> Vrow bf16.
// ---------------------------------------------------------------------------
__global__ __launch_bounds__(256) void gemm_qkv(const ushort* __restrict__ xb,
                                                const ushort* __restrict__ WT,
                                                const float* __restrict__ bq,
                                                const float* __restrict__ bk,
                                                const float* __restrict__ bv,
                                                ushort* __restrict__ Qext,
                                                ushort* __restrict__ Kext,
                                                ushort* __restrict__ Vrow) {
    __shared__ ushort smem[2][128][72];   // As=smem[0], Bs=smem[1]; 36.9KB
    ushort (*As)[72] = smem[0];
    ushort (*Bs)[72] = smem[1];
    const int tid = threadIdx.x;
    const int lane = tid & 63, wave = tid >> 6;
    const int col = lane & 15, quad = lane >> 4;
    const int wm = wave >> 1, wn = wave & 1;
    const int id = blockIdx.x >> 3;               // 0:Q 1:K 2:V
    const int n0 = (blockIdx.x & 7) * 128;
    const int m0 = blockIdx.y * 128;
    const ushort* BTw = WT + (size_t)id * Dd * Dd;
    const float* bias = id == 0 ? bq : id == 1 ? bk : bv;

    f32x4 acc[4][4] = {};

    for (int k0 = 0; k0 < Dd; k0 += 64) {
        __syncthreads();
#pragma unroll
        for (int i = 0; i < 4; ++i) {
            int f = tid + i * 256;          // 0..1023
            int r = f >> 3, c = (f & 7) * 8;
            *(int4*)&As[r][c] = *(const int4*)(xb + (size_t)(m0 + r) * Dd + k0 + c);
            *(int4*)&Bs[r][c] = *(const int4*)(BTw + (size_t)(n0 + r) * Dd + k0 + c);
        }
        __syncthreads();
#pragma unroll
        for (int kk = 0; kk < 2; ++kk) {
            short8 af[4], bf[4];
#pragma unroll
            for (int i = 0; i < 4; ++i) {
                af[i] = *(const short8*)&As[wm * 64 + i * 16 + col][kk * 32 + quad * 8];
                bf[i] = *(const short8*)&Bs[wn * 64 + i * 16 + col][kk * 32 + quad * 8];
            }
#pragma unroll
            for (int i = 0; i < 4; ++i)
#pragma unroll
                for (int j = 0; j < 4; ++j)
                    acc[i][j] = __builtin_amdgcn_mfma_f32_16x16x32_bf16(af[i], bf[j], acc[i][j], 0, 0, 0);
        }
    }

    // ---- coalesced epilogue via LDS ----
    __syncthreads();                               // As/Bs reads all done
    ushort (*Ep)[136] = (ushort (*)[136])&smem[0][0][0];   // 128x136 = 34.8KB
    const float scl = (id == 0) ? 0.125f : 1.0f;
#pragma unroll
    for (int j = 0; j < 4; ++j) {
        int n_local = wn * 64 + j * 16 + col;
        float bvl = bias[n0 + n_local];
#pragma unroll
        for (int i = 0; i < 4; ++i) {
            int mb = wm * 64 + i * 16 + quad * 4;
#pragma unroll
            for (int reg = 0; reg < 4; ++reg)
                Ep[mb + reg][n_local] = f2bf((acc[i][j][reg] + bvl) * scl);
        }
    }
    __syncthreads();
    {
        const int mrow = tid >> 1;               // 0..127 local s
        const int half = tid & 1;                // which head of the 2 in n-range
        const int b = m0 >> 11, s = (m0 & (Ss - 1)) + mrow;
        const int hh = (n0 >> 6) + half;
        if (id == 2) {
            ushort* drow = Vrow + ((size_t)(b * Hh + hh) * Ss + s) * 64;
#pragma unroll
            for (int k = 0; k < 8; ++k)
                *(int4*)(drow + k * 8) = *(int4*)&Ep[mrow][half * 64 + k * 8];
        } else {
            ushort* drow = (id == 0 ? Qext : Kext) + ((size_t)(b * Hh + hh) * Ss + s) * 128;
#pragma unroll
            for (int k = 0; k < 8; ++k)
                *(int4*)(drow + k * 8) = *(int4*)&Ep[mrow][half * 64 + k * 8];
        }
    }
}

// ---------------------------------------------------------------------------
// Output projection: out[M][N] f32 = abb(bf16) @ WoT + bo (round-8 version).
// ---------------------------------------------------------------------------
__global__ __launch_bounds__(256) void gemm_out(const ushort* __restrict__ Ab,
                                                const ushort* __restrict__ BT,
                                                const float* __restrict__ bias,
                                                float* __restrict__ C) {
    __shared__ ushort As[128][72];
    __shared__ ushort Bs[128][72];
    const int tid = threadIdx.x;
    const int lane = tid & 63, wave = tid >> 6;
    const int col = lane & 15, quad = lane >> 4;
    const int wm = wave >> 1, wn = wave & 1;
    const int n0 = blockIdx.x * 128;
    const int m0 = blockIdx.y * 128;

    f32x4 acc[4][4] = {};

    for (int k0 = 0; k0 < Dd; k0 += 64) {
        __syncthreads();
#pragma unroll
        for (int i = 0; i < 4; ++i) {
            int f = tid + i * 256;
            int r = f >> 3, c = (f & 7) * 8;
            *(int4*)&As[r][c] = *(const int4*)(Ab + (size_t)(m0 + r) * Dd + k0 + c);
            *(int4*)&Bs[r][c] = *(const int4*)(BT + (size_t)(n0 + r) * Dd + k0 + c);
        }
        __syncthreads();
#pragma unroll
        for (int kk = 0; kk < 2; ++kk) {
            short8 af[4], bf[4];
#pragma unroll
            for (int i = 0; i < 4; ++i) {
                af[i] = *(const short8*)&As[wm * 64 + i * 16 + col][kk * 32 + quad * 8];
                bf[i] = *(const short8*)&Bs[wn * 64 + i * 16 + col][kk * 32 + quad * 8];
            }
#pragma unroll
            for (int i = 0; i < 4; ++i)
#pragma unroll
                for (int j = 0; j < 4; ++j)
                    acc[i][j] = __builtin_amdgcn_mfma_f32_16x16x32_bf16(af[i], bf[j], acc[i][j], 0, 0, 0);
        }
    }

#pragma unroll
    for (int j = 0; j < 4; ++j) {
        int n = n0 + wn * 64 + j * 16 + col;
        float bvl = bias[n];
#pragma unroll
        for (int i = 0; i < 4; ++i) {
#pragma unroll
            for (int reg = 0; reg < 4; ++reg) {
                int m = m0 + wm * 64 + i * 16 + quad * 4 + reg;
                C[(size_t)m * Dd + n] = acc[i][j][reg] + bvl;
            }
        }
    }
}

// ---------------------------------------------------------------------------
// Flash attention v7: round-8 per-wave structure, 8 WAVES (512 threads).
// Each wave owns a 16-row strip of BQ=128; staging tiles amortized over 8
// waves; waves/CU 8 -> 16 (latency-bound fix per r11 occupancy analysis).
// S^T = Kext (A) x Qext (B); fixed-shift softmax p=exp(s-8); RNE P pack.
// ---------------------------------------------------------------------------
#define ABQ 128

__global__ __launch_bounds__(512) void attn_mfma7(const ushort* __restrict__ Qe,
                                                  const ushort* __restrict__ Ke,
                                                  const ushort* __restrict__ Vt,
                                                  ushort* __restrict__ Ob) {
    __shared__ ushort Ks[64][136];       // K-ext tile [key][128+8pad]  17.4KB
    __shared__ ushort Vts[64][72];       // V^T tile [d][64key+8pad]     9.2KB
    __shared__ ushort PsT[8][16][72];    // per-wave P^T [q][64keys+8]  18.4KB

    const int tid = threadIdx.x;
    const int wave = tid >> 6, lane = tid & 63;
    const int col = lane & 15, quad = lane >> 4;
    const int qt = (gridDim.x - 1) - blockIdx.x;   // long blocks first
    const int h = blockIdx.y, b = blockIdx.z;
    const int bh = b * Hh + h;
    const int q0 = qt * ABQ;
    const int rowb = q0 + wave * 16;     // this wave's 16-row strip

    // Q fragments (K=128) for this wave's strip; MFMA B operand.
    short8 qf[4];
    {
        const ushort* qp = Qe + ((size_t)bh * Ss + rowb + col) * 128 + quad * 8;
#pragma unroll
        for (int k0 = 0; k0 < 4; ++k0) qf[k0] = *(const short8*)(qp + k0 * 32);
    }

    const f32x4 zero4 = {0.f, 0.f, 0.f, 0.f};
    f32x4 oaccT[4] = {zero4, zero4, zero4, zero4};
    float lsum = 0.f;                    // per-lane: q = rowb + col

    const ushort* Kbase = Ke + (size_t)bh * Ss * 128;
    const ushort* Vbase = Vt + (size_t)bh * 64 * Ss;

    const int ntiles = 2 * qt + 2;
    for (int t = 0; t < ntiles; ++t) {
        const int j0 = t * 64;
        __syncthreads();
        // K tile: 1024 int4, 512 threads x 2
#pragma unroll
        for (int i = 0; i < 2; ++i) {
            int f = tid + i * 512;
            int r = f >> 4, ch = f & 15;
            *(int4*)&Ks[r][ch * 8] = *(const int4*)(Kbase + (size_t)(j0 + r) * 128 + ch * 8);
        }
        // V tile: 512 int4, 1 per thread
        {
            int d = tid >> 3, ch = tid & 7;
            *(int4*)&Vts[d][ch * 8] = *(const int4*)(Vbase + (size_t)d * Ss + j0 + ch * 8);
        }
        __syncthreads();

        if (j0 > rowb + 15) continue;        // strip fully masked for this tile

        // S^T tiles: c tiles the KEY dim (4 x 16 keys), q = col
        f32x4 sacc[4] = {zero4, zero4, zero4, zero4};
#pragma unroll
        for (int c = 0; c < 4; ++c)
#pragma unroll
            for (int k0 = 0; k0 < 4; ++k0) {
                short8 kf = *(const short8*)&Ks[c * 16 + col][k0 * 32 + quad * 8];
                sacc[c] = __builtin_amdgcn_mfma_f32_16x16x32_bf16(kf, qf[k0], sacc[c], 0, 0, 0);
            }

        const bool diag = (j0 + 63 >= rowb);     // tile crosses this strip's diagonal
        const int qrow_rel = rowb + col - j0;    // mask: key_rel > qrow_rel
#pragma unroll
        for (int c = 0; c < 4; ++c) {
#pragma unroll
            for (int reg = 0; reg < 4; ++reg) {
                float s = sacc[c][reg];
                if (diag && (c * 16 + quad * 4 + reg > qrow_rel)) s = -1e9f;
                float p = __expf(fminf(s, 20.f) - 8.0f);
                lsum += p;
                sacc[c][reg] = p;
            }
            uint2 pk;
            pk.x = (uint)f2bf(sacc[c][0]) | ((uint)f2bf(sacc[c][1]) << 16);
            pk.y = (uint)f2bf(sacc[c][2]) | ((uint)f2bf(sacc[c][3]) << 16);
            *(uint2*)&PsT[wave][col][c * 16 + quad * 4] = pk;
        }

        // PV: O^T += V^T (A) x P^T (B); per-wave LDS round-trip (DS in-order)
#pragma unroll
        for (int k0 = 0; k0 < 2; ++k0) {
            short8 ptf = *(const short8*)&PsT[wave][col][k0 * 32 + quad * 8];
#pragma unroll
            for (int c2 = 0; c2 < 4; ++c2) {
                short8 vtf = *(const short8*)&Vts[c2 * 16 + col][k0 * 32 + quad * 8];
                oaccT[c2] = __builtin_amdgcn_mfma_f32_16x16x32_bf16(vtf, ptf, oaccT[c2], 0, 0, 0);
            }
        }
    }

    // epilogue: O[q][d], q = rowb+col, d = c2*16 + quad*4 + reg
    {
        float l = lsum;
        l += __shfl_xor(l, 16, 64);
        l += __shfl_xor(l, 32, 64);              // sum over the 4 quads (same col)
        const float inv = 1.f / l;
        ushort* dst = Ob + ((size_t)b * Ss + rowb + col) * Dd + h * DK + quad * 4;
#pragma unroll
        for (int c2 = 0; c2 < 4; ++c2) {
            uint2 pk;
            pk.x = (uint)f2bf(oaccT[c2][0] * inv) | ((uint)f2bf(oaccT[c2][1] * inv) << 16);
            pk.y = (uint)f2bf(oaccT[c2][2] * inv) | ((uint)f2bf(oaccT[c2][3] * inv) << 16);
            *(uint2*)(dst + c2 * 16) = pk;
        }
    }
}

// ---------------------------------------------------------------------------
extern "C" void kernel_launch(void* const* d_in, const int* in_sizes, int n_in,
                              void* d_out, int out_size, void* d_ws, size_t ws_size,
                              hipStream_t stream) {
    const float* x            = (const float*)d_in[0];
    const float* features     = (const float*)d_in[1];
    const float* requirements = (const float*)d_in[2];
    const float* Wq = (const float*)d_in[3];
    const float* bq = (const float*)d_in[4];
    const float* Wk = (const float*)d_in[5];
    const float* bk = (const float*)d_in[6];
    const float* Wv = (const float*)d_in[7];
    const float* bv = (const float*)d_in[8];
    const float* Wo = (const float*)d_in[9];
    const float* bo = (const float*)d_in[10];

    float* out = (float*)d_out;
    float* ws = (float*)d_ws;

    // workspace layout (float offsets)
    ushort* xb   = (ushort*)(ws);                 // [4096,1024] bf16, 8MB
    ushort* WT   = (ushort*)(ws + 2097152);       // [4][1024][1024] bf16, 8MB
    ushort* Qext = (ushort*)(ws + 4194304);       // [32][2048][128] bf16, 16MB
    ushort* Kext = (ushort*)(ws + 8388608);       // 16MB
    ushort* Vrow = (ushort*)(ws + 12582912);      // [32][2048][64] bf16, 8MB
    ushort* Vt   = (ushort*)(ws + 16777216);      // [32][64][2048] bf16, 8MB
    float*  fn   =           ws + 18874368;       // [4096][64] f32
    float*  rn   =           ws + 19136512;
    ushort* abb  = (ushort*)(ws + 12582912);      // attn out bf16, reuses Vrow (dead after pack_vt)

    cast_bf16<<<8192, 256, 0, stream>>>(x, xb);
    transpose_cast4<<<dim3(16, 16, 4), 256, 0, stream>>>(Wq, Wk, Wv, Wo, WT);
    l2norm2<<<2048, 256, 0, stream>>>(features, requirements, fn, rn);
    pack_aux<<<8192, 256, 0, stream>>>(rn, fn, Qext, Kext);

    gemm_qkv<<<dim3(24, 32), 256, 0, stream>>>(xb, WT, bq, bk, bv, Qext, Kext, Vrow);
    pack_vt<<<dim3(Ss / 64, Hh, Bb), 256, 0, stream>>>(Vrow, Vt);

    attn_mfma7<<<dim3(Ss / ABQ, Hh, Bb), 512, 0, stream>>>(Qext, Kext, Vt, abb);

    gemm_out<<<dim3(8, 32), 256, 0, stream>>>(abb, WT + (size_t)3 * Dd * Dd, bo, out);
}